// Round 7
// baseline (727.796 us; speedup 1.0000x reference)
//
#include <hip/hip_runtime.h>
#include <hip/hip_cooperative_groups.h>

namespace cg = cooperative_groups;

// SimpleGraphSAGE: out = mean_agg(x[src]->dst) @ W_l + b_l + x @ W_r
// N=50000, E=640000, IN=128, HID=256.
// R7: collapse the 6-kernel CSR+agg pipeline into ONE cooperative kernel
// (grid-stride phases + grid.sync), killing ~5 launch gaps + memset dispatch.
// gemm_k (R6 one-barrier MFMA) stays separate to keep its own occupancy.
// Fallback to the R6 multi-kernel path if cooperative launch is unavailable.

constexpr int N_NODES = 50000;
constexpr int N_EDGES = 640000;
constexpr int SCAN_BLOCKS = (N_NODES + 256) / 256;  // 196, covers i==N_NODES

constexpr int HIST_BLOCKS  = N_EDGES / 1024;        // fallback prep partitions
constexpr int PREPX_BLOCKS = N_NODES * 32 / 256;
constexpr int WPREP_BLOCKS = 256;

typedef __attribute__((ext_vector_type(8))) short short8;
typedef __attribute__((ext_vector_type(4))) float f32x4;

__device__ inline unsigned short f2bf(float f) {
    unsigned int u = __float_as_uint(f);
    u += 0x7fff + ((u >> 16) & 1);  // RNE
    return (unsigned short)(u >> 16);
}
__device__ inline float bf2f(unsigned int s) {
    return __uint_as_float(s << 16);
}

// ---------------------------------------------------------------------------
// build_k (cooperative): zero -> hist+prep -> scan -> permute -> agg
// Abf row layout: [0..127]=mean, [128..255]=bf16(x row)
// ---------------------------------------------------------------------------
__global__ __launch_bounds__(256, 8) void build_k(
        const float* __restrict__ x, const int* __restrict__ ei,
        const float* __restrict__ Wl, const float* __restrict__ Wr,
        unsigned int* __restrict__ Abf_u, unsigned short* __restrict__ Wimg,
        int* __restrict__ cnt, int* __restrict__ row_start,
        int* __restrict__ cursor, int* __restrict__ sorted_src) {
    cg::grid_group grid = cg::this_grid();
    __shared__ int lds[8];

    int tid  = threadIdx.x;
    int gtid = blockIdx.x * 256 + tid;
    int gstr = gridDim.x * 256;
    int lane = tid & 63, wv = tid >> 6;

    // ---- P0: zero cnt ----
    for (int i = gtid; i < N_NODES; i += gstr) cnt[i] = 0;
    grid.sync();

    // ---- P1: hist + x->bf16 + W tile ----
    for (int e = gtid; e < N_EDGES; e += gstr)
        atomicAdd(&cnt[ei[N_EDGES + e]], 1);
    for (int t = gtid; t < N_NODES * 32; t += gstr) {
        float4 v = reinterpret_cast<const float4*>(x)[t];
        unsigned int p0 = (unsigned int)f2bf(v.x) | ((unsigned int)f2bf(v.y) << 16);
        unsigned int p1 = (unsigned int)f2bf(v.z) | ((unsigned int)f2bf(v.w) << 16);
        int row = t >> 5, c = t & 31;
        reinterpret_cast<uint2*>(Abf_u)[(size_t)row * 64 + 32 + c] =
            make_uint2(p0, p1);
    }
    for (int t = gtid; t < 65536; t += gstr) {
        int k = t >> 8, n = t & 255;
        float v = (k < 128) ? Wl[k * 256 + n] : Wr[(k - 128) * 256 + n];
        Wimg[(size_t)(k >> 5) * 8192 + n * 32 + (k & 31)] = f2bf(v);
    }
    grid.sync();

    // ---- P2: full exclusive scan, one phase (196 block-units) ----
    for (int b = blockIdx.x; b < SCAN_BLOCKS; b += gridDim.x) {
        int lim = b * 256;
        int acc = 0;
        for (int j = tid; j < lim; j += 256) acc += cnt[j];
#pragma unroll
        for (int m = 1; m < 64; m <<= 1) acc += __shfl_xor(acc, m, 64);
        if (lane == 0) lds[wv] = acc;
        __syncthreads();
        int prefix = lds[0] + lds[1] + lds[2] + lds[3];

        int i = lim + tid;
        int v = (i < N_NODES) ? cnt[i] : 0;
        int inc = v;
#pragma unroll
        for (int off = 1; off < 64; off <<= 1) {
            int t2 = __shfl_up(inc, off, 64);
            if (lane >= off) inc += t2;
        }
        if (lane == 63) lds[4 + wv] = inc;
        __syncthreads();
        int woff = 0;
        for (int j = 0; j < wv; j++) woff += lds[4 + j];
        int rs = prefix + woff + (inc - v);
        if (i < N_NODES) {
            row_start[i] = rs;
            cursor[i]    = rs;
        }
        if (i == N_NODES) row_start[N_NODES] = rs;
        __syncthreads();
    }
    grid.sync();

    // ---- P3: permute src into dst-sorted order ----
    for (int e = gtid; e < N_EDGES; e += gstr) {
        int dst = ei[N_EDGES + e];
        int pos = atomicAdd(&cursor[dst], 1);
        sorted_src[pos] = ei[e];
    }
    grid.sync();

    // ---- P4: aggregate, one wave per node ----
    int gw = gtid >> 6;
    int nw = gstr >> 6;
    int g = lane >> 4, sub = lane & 15;
    const uint4* X = reinterpret_cast<const uint4*>(Abf_u);
    for (int wid = gw; wid < N_NODES; wid += nw) {
        int beg = row_start[wid];
        int end = row_start[wid + 1];
        float s[8];
#pragma unroll
        for (int j = 0; j < 8; j++) s[j] = 0.f;
        for (int i = beg; i < end; i += 8) {
            int e0 = i + g;
            int e1 = i + 4 + g;
            uint4 v0 = make_uint4(0, 0, 0, 0), v1 = make_uint4(0, 0, 0, 0);
            if (e0 < end) v0 = X[(size_t)sorted_src[e0] * 32 + 16 + sub];
            if (e1 < end) v1 = X[(size_t)sorted_src[e1] * 32 + 16 + sub];
            s[0] += bf2f(v0.x & 0xffffu) + bf2f(v1.x & 0xffffu);
            s[1] += bf2f(v0.x >> 16)     + bf2f(v1.x >> 16);
            s[2] += bf2f(v0.y & 0xffffu) + bf2f(v1.y & 0xffffu);
            s[3] += bf2f(v0.y >> 16)     + bf2f(v1.y >> 16);
            s[4] += bf2f(v0.z & 0xffffu) + bf2f(v1.z & 0xffffu);
            s[5] += bf2f(v0.z >> 16)     + bf2f(v1.z >> 16);
            s[6] += bf2f(v0.w & 0xffffu) + bf2f(v1.w & 0xffffu);
            s[7] += bf2f(v0.w >> 16)     + bf2f(v1.w >> 16);
        }
#pragma unroll
        for (int m = 16; m <= 32; m <<= 1)
#pragma unroll
            for (int j = 0; j < 8; j++) s[j] += __shfl_xor(s[j], m, 64);
        if (g == 0) {
            float inv = (end > beg) ? 1.0f / (float)(end - beg) : 0.0f;
            uint4 o;
            o.x = (unsigned int)f2bf(s[0] * inv) | ((unsigned int)f2bf(s[1] * inv) << 16);
            o.y = (unsigned int)f2bf(s[2] * inv) | ((unsigned int)f2bf(s[3] * inv) << 16);
            o.z = (unsigned int)f2bf(s[4] * inv) | ((unsigned int)f2bf(s[5] * inv) << 16);
            o.w = (unsigned int)f2bf(s[6] * inv) | ((unsigned int)f2bf(s[7] * inv) << 16);
            reinterpret_cast<uint4*>(Abf_u)[(size_t)wid * 32 + sub] = o;
        }
    }
}

// ---------------------------------------------------------------------------
// Fallback kernels (R6) — used only if cooperative launch is unavailable.
// ---------------------------------------------------------------------------
__global__ __launch_bounds__(256) void prep_k(const float* __restrict__ x,
                                              const int* __restrict__ ei,
                                              const float* __restrict__ Wl,
                                              const float* __restrict__ Wr,
                                              unsigned int* __restrict__ Abf_u,
                                              unsigned short* __restrict__ Wimg,
                                              int* __restrict__ cnt) {
    int bid = blockIdx.x, tid = threadIdx.x;
    if (bid < HIST_BLOCKS) {
        int base = bid * 1024 + tid;
#pragma unroll
        for (int k = 0; k < 4; k++)
            atomicAdd(&cnt[ei[N_EDGES + base + k * 256]], 1);
    } else if (bid < HIST_BLOCKS + PREPX_BLOCKS) {
        int t = (bid - HIST_BLOCKS) * 256 + tid;
        float4 v = reinterpret_cast<const float4*>(x)[t];
        unsigned int p0 = (unsigned int)f2bf(v.x) | ((unsigned int)f2bf(v.y) << 16);
        unsigned int p1 = (unsigned int)f2bf(v.z) | ((unsigned int)f2bf(v.w) << 16);
        int row = t >> 5, c = t & 31;
        reinterpret_cast<uint2*>(Abf_u)[(size_t)row * 64 + 32 + c] =
            make_uint2(p0, p1);
    } else {
        int t = (bid - HIST_BLOCKS - PREPX_BLOCKS) * 256 + tid;
        int k = t >> 8, n = t & 255;
        float v = (k < 128) ? Wl[k * 256 + n] : Wr[(k - 128) * 256 + n];
        Wimg[(size_t)(k >> 5) * 8192 + n * 32 + (k & 31)] = f2bf(v);
    }
}

__global__ __launch_bounds__(256) void scan_full_k(const int* __restrict__ cnt,
                                                   int* __restrict__ row_start,
                                                   int* __restrict__ cursor) {
    __shared__ int lds[8];
    int tid = threadIdx.x, lane = tid & 63, wv = tid >> 6;
    int b = (int)blockIdx.x;
    int lim = b * 256;
    int acc = 0;
    for (int j = tid; j < lim; j += 256) acc += cnt[j];
#pragma unroll
    for (int m = 1; m < 64; m <<= 1) acc += __shfl_xor(acc, m, 64);
    if (lane == 0) lds[wv] = acc;
    __syncthreads();
    int prefix = lds[0] + lds[1] + lds[2] + lds[3];
    int i = lim + tid;
    int v = (i < N_NODES) ? cnt[i] : 0;
    int inc = v;
#pragma unroll
    for (int off = 1; off < 64; off <<= 1) {
        int t2 = __shfl_up(inc, off, 64);
        if (lane >= off) inc += t2;
    }
    if (lane == 63) lds[4 + wv] = inc;
    __syncthreads();
    int woff = 0;
    for (int j = 0; j < wv; j++) woff += lds[4 + j];
    int rs = prefix + woff + (inc - v);
    if (i < N_NODES) {
        row_start[i] = rs;
        cursor[i]    = rs;
    }
    if (i == N_NODES) row_start[N_NODES] = rs;
}

__global__ __launch_bounds__(256) void permute_k(const int* __restrict__ ei,
                                                 int* __restrict__ cursor,
                                                 int* __restrict__ sorted_src) {
    int e = blockIdx.x * 256 + threadIdx.x;
    if (e >= N_EDGES) return;
    int dst = ei[N_EDGES + e];
    int pos = atomicAdd(&cursor[dst], 1);
    sorted_src[pos] = ei[e];
}

__global__ __launch_bounds__(256) void agg_k(const int* __restrict__ row_start,
                                             const int* __restrict__ sorted_src,
                                             unsigned int* __restrict__ Abf_u) {
    int wid  = (blockIdx.x * 256 + threadIdx.x) >> 6;
    int lane = threadIdx.x & 63;
    int g    = lane >> 4;
    int sub  = lane & 15;
    int beg = row_start[wid];
    int end = row_start[wid + 1];
    const uint4* X = reinterpret_cast<const uint4*>(Abf_u);
    float s[8];
#pragma unroll
    for (int j = 0; j < 8; j++) s[j] = 0.f;
    for (int i = beg; i < end; i += 8) {
        int e0 = i + g;
        int e1 = i + 4 + g;
        uint4 v0 = make_uint4(0, 0, 0, 0), v1 = make_uint4(0, 0, 0, 0);
        if (e0 < end) v0 = X[(size_t)sorted_src[e0] * 32 + 16 + sub];
        if (e1 < end) v1 = X[(size_t)sorted_src[e1] * 32 + 16 + sub];
        s[0] += bf2f(v0.x & 0xffffu) + bf2f(v1.x & 0xffffu);
        s[1] += bf2f(v0.x >> 16)     + bf2f(v1.x >> 16);
        s[2] += bf2f(v0.y & 0xffffu) + bf2f(v1.y & 0xffffu);
        s[3] += bf2f(v0.y >> 16)     + bf2f(v1.y >> 16);
        s[4] += bf2f(v0.z & 0xffffu) + bf2f(v1.z & 0xffffu);
        s[5] += bf2f(v0.z >> 16)     + bf2f(v1.z >> 16);
        s[6] += bf2f(v0.w & 0xffffu) + bf2f(v1.w & 0xffffu);
        s[7] += bf2f(v0.w >> 16)     + bf2f(v1.w >> 16);
    }
#pragma unroll
    for (int m = 16; m <= 32; m <<= 1)
#pragma unroll
        for (int j = 0; j < 8; j++) s[j] += __shfl_xor(s[j], m, 64);
    if (g == 0) {
        float inv = (end > beg) ? 1.0f / (float)(end - beg) : 0.0f;
        uint4 o;
        o.x = (unsigned int)f2bf(s[0] * inv) | ((unsigned int)f2bf(s[1] * inv) << 16);
        o.y = (unsigned int)f2bf(s[2] * inv) | ((unsigned int)f2bf(s[3] * inv) << 16);
        o.z = (unsigned int)f2bf(s[4] * inv) | ((unsigned int)f2bf(s[5] * inv) << 16);
        o.w = (unsigned int)f2bf(s[6] * inv) | ((unsigned int)f2bf(s[7] * inv) << 16);
        reinterpret_cast<uint4*>(Abf_u)[(size_t)wid * 32 + sub] = o;
    }
}

// ---------------------------------------------------------------------------
// gemm_k (R6): stage full 64x256 A-tile, ONE barrier, barrier-free K-loop,
// B-frags straight from L2-resident Wimg.
// ---------------------------------------------------------------------------
__global__ __launch_bounds__(256) void gemm_k(const unsigned short* __restrict__ Abf,
                                              const unsigned short* __restrict__ Wimg,
                                              const float* __restrict__ bl,
                                              float* __restrict__ out) {
    __shared__ unsigned short As[64 * 264];

    int tid  = threadIdx.x;
    int w    = tid >> 6;
    int lane = tid & 63;
    int m15  = lane & 15;
    int quad = lane >> 4;
    int bm   = blockIdx.x * 64;

#pragma unroll
    for (int s = 0; s < 8; s++) {
        int idx = s * 256 + tid;
        int r = idx >> 5, c = idx & 31;
        int grow = bm + r;
        short8 v = {0, 0, 0, 0, 0, 0, 0, 0};
        if (grow < N_NODES)
            v = *reinterpret_cast<const short8*>(Abf + (size_t)grow * 256 + c * 8);
        *reinterpret_cast<short8*>(As + r * 264 + c * 8) = v;
    }
    __syncthreads();

    f32x4 zero4 = {0.f, 0.f, 0.f, 0.f};
    f32x4 acc[4][4];
#pragma unroll
    for (int rt = 0; rt < 4; rt++)
#pragma unroll
        for (int ct = 0; ct < 4; ct++) acc[rt][ct] = zero4;

#pragma unroll
    for (int kc = 0; kc < 8; kc++) {
        short8 Af[4], Bf[4];
#pragma unroll
        for (int rt = 0; rt < 4; rt++)
            Af[rt] = *reinterpret_cast<const short8*>(
                         As + (rt * 16 + m15) * 264 + kc * 32 + quad * 8);
#pragma unroll
        for (int ct = 0; ct < 4; ct++)
            Bf[ct] = *reinterpret_cast<const short8*>(
                         Wimg + (size_t)kc * 8192 +
                         (w * 64 + ct * 16 + m15) * 32 + quad * 8);
#pragma unroll
        for (int rt = 0; rt < 4; rt++)
#pragma unroll
            for (int ct = 0; ct < 4; ct++)
                acc[rt][ct] = __builtin_amdgcn_mfma_f32_16x16x32_bf16(
                    Af[rt], Bf[ct], acc[rt][ct], 0, 0, 0);
    }

    float bias[4];
#pragma unroll
    for (int ct = 0; ct < 4; ct++) bias[ct] = bl[w * 64 + ct * 16 + m15];
#pragma unroll
    for (int rt = 0; rt < 4; rt++) {
        int rb = bm + rt * 16 + quad * 4;
#pragma unroll
        for (int r = 0; r < 4; r++) {
            int row = rb + r;
            if (row < N_NODES) {
#pragma unroll
                for (int ct = 0; ct < 4; ct++)
                    out[(size_t)row * 256 + w * 64 + ct * 16 + m15] =
                        acc[rt][ct][r] + bias[ct];
            }
        }
    }
}

extern "C" void kernel_launch(void* const* d_in, const int* in_sizes, int n_in,
                              void* d_out, int out_size, void* d_ws, size_t ws_size,
                              hipStream_t stream) {
    const float* x  = (const float*)d_in[0];
    const int*   ei = (const int*)d_in[1];   // [2, E] int32
    const float* Wl = (const float*)d_in[2];
    const float* bl = (const float*)d_in[3];
    const float* Wr = (const float*)d_in[4];
    float* out = (float*)d_out;

    // ws layout
    unsigned short* Abf  = (unsigned short*)d_ws;              // N*256 bf16
    unsigned short* Wimg = Abf + (size_t)N_NODES * 256;        // 65536 bf16
    int* cnt        = (int*)(Wimg + 65536);                    // N
    int* row_start  = cnt + N_NODES;                           // N+1
    int* cursor     = row_start + N_NODES + 1;                 // N
    int* blockSums  = cursor + N_NODES;                        // 256 (unused now)
    int* sorted_src = blockSums + 256;                         // E

    // cooperative capability + occupancy (host-side queries, capture-safe,
    // deterministic across calls)
    int dev = 0;
    hipGetDevice(&dev);
    int coop = 0;
    hipDeviceGetAttribute(&coop, hipDeviceAttributeCooperativeLaunch, dev);
    int ncu = 0;
    hipDeviceGetAttribute(&ncu, hipDeviceAttributeMultiprocessorCount, dev);
    int blocksPerCU = 0;
    hipError_t oe = hipOccupancyMaxActiveBlocksPerMultiprocessor(
        &blocksPerCU, (const void*)build_k, 256, 0);

    if (coop && oe == hipSuccess && blocksPerCU > 0 && ncu > 0) {
        int grid = blocksPerCU * ncu;
        if (grid > 4096) grid = 4096;
        void* args[] = {(void*)&x, (void*)&ei, (void*)&Wl, (void*)&Wr,
                        (void*)&Abf, (void*)&Wimg, (void*)&cnt, (void*)&row_start,
                        (void*)&cursor, (void*)&sorted_src};
        hipLaunchCooperativeKernel((const void*)build_k, dim3(grid), dim3(256),
                                   args, 0, stream);
    } else {
        // R6 fallback path
        hipMemsetAsync(cnt, 0, N_NODES * sizeof(int), stream);
        prep_k<<<HIST_BLOCKS + PREPX_BLOCKS + WPREP_BLOCKS, 256, 0, stream>>>(
            x, ei, Wl, Wr, (unsigned int*)Abf, Wimg, cnt);
        scan_full_k<<<SCAN_BLOCKS, 256, 0, stream>>>(cnt, row_start, cursor);
        permute_k<<<(N_EDGES + 255) / 256, 256, 0, stream>>>(ei, cursor, sorted_src);
        agg_k<<<(N_NODES * 64) / 256, 256, 0, stream>>>(row_start, sorted_src,
                                                        (unsigned int*)Abf);
    }
    gemm_k<<<(N_NODES + 63) / 64, 256, 0, stream>>>(Abf, Wimg, bl, out);
}

// Round 9
// 206.046 us; speedup vs baseline: 3.5322x; 3.5322x over previous
//
#include <hip/hip_runtime.h>

// SimpleGraphSAGE: out = mean_agg(x[src]->dst) @ W_l + b_l + x @ W_r
// N=50000, E=640000, IN=128, HID=256.
// R9: R8's windowed-__shfl agg had UB (shfl source lane inactive in the
// divergent tail-window branch -> undefined, absmax 0.246). Revert agg_k to
// the R6-proven form. KEEP the two sound R8 changes: rank-trick atomic-free
// permute, and single merged scan kernel (one fewer dispatch).

constexpr int N_NODES = 50000;
constexpr int N_EDGES = 640000;
constexpr int SCAN_BLOCKS = (N_NODES + 256) / 256;  // 196, covers i==N_NODES

constexpr int HIST_BLOCKS  = N_EDGES / 256;         // 2500: 1 edge/thread
constexpr int PREPX_BLOCKS = N_NODES * 32 / 256;    // 6250: thread = 4 channels
constexpr int WPREP_BLOCKS = 256;                   // 65536 weight elems

typedef __attribute__((ext_vector_type(8))) short short8;
typedef __attribute__((ext_vector_type(4))) float f32x4;

__device__ inline unsigned short f2bf(float f) {
    unsigned int u = __float_as_uint(f);
    u += 0x7fff + ((u >> 16) & 1);  // RNE
    return (unsigned short)(u >> 16);
}
__device__ inline float bf2f(unsigned int s) {
    return __uint_as_float(s << 16);
}

// ---------------------------------------------------------------------------
// prep_k: block-range fused  [hist+rank | x->bf16 | W->bf16 tiled]
// Abf row layout: [0..127]=mean (agg_k), [128..255]=bf16(x row)
// ---------------------------------------------------------------------------
__global__ __launch_bounds__(256) void prep_k(const float* __restrict__ x,
                                              const int* __restrict__ ei,
                                              const float* __restrict__ Wl,
                                              const float* __restrict__ Wr,
                                              unsigned int* __restrict__ Abf_u,
                                              unsigned short* __restrict__ Wimg,
                                              int* __restrict__ cnt,
                                              int* __restrict__ rank) {
    int bid = blockIdx.x, tid = threadIdx.x;
    if (bid < HIST_BLOCKS) {
        int e = bid * 256 + tid;
        rank[e] = atomicAdd(&cnt[ei[N_EDGES + e]], 1);
    } else if (bid < HIST_BLOCKS + PREPX_BLOCKS) {
        int t = (bid - HIST_BLOCKS) * 256 + tid;          // < N*32
        float4 v = reinterpret_cast<const float4*>(x)[t];
        unsigned int p0 = (unsigned int)f2bf(v.x) | ((unsigned int)f2bf(v.y) << 16);
        unsigned int p1 = (unsigned int)f2bf(v.z) | ((unsigned int)f2bf(v.w) << 16);
        int row = t >> 5, c = t & 31;
        reinterpret_cast<uint2*>(Abf_u)[(size_t)row * 64 + 32 + c] =
            make_uint2(p0, p1);
    } else {
        int t = (bid - HIST_BLOCKS - PREPX_BLOCKS) * 256 + tid;  // < 65536
        int k = t >> 8, n = t & 255;
        float v = (k < 128) ? Wl[k * 256 + n] : Wr[(k - 128) * 256 + n];
        Wimg[(size_t)(k >> 5) * 8192 + n * 32 + (k & 31)] = f2bf(v);
    }
}

// ---------------------------------------------------------------------------
// scan_full_k: one kernel. Block b: prefix = sum(cnt[0 .. 256b)), then
// wave-shfl scan of its own 256 counts -> row_start.
// ---------------------------------------------------------------------------
__global__ __launch_bounds__(256) void scan_full_k(const int* __restrict__ cnt,
                                                   int* __restrict__ row_start) {
    __shared__ int lds[8];
    int tid = threadIdx.x, lane = tid & 63, wv = tid >> 6;
    int b = (int)blockIdx.x;
    int lim = b * 256;
    int acc = 0;
    for (int j = tid; j < lim; j += 256) acc += cnt[j];
#pragma unroll
    for (int m = 1; m < 64; m <<= 1) acc += __shfl_xor(acc, m, 64);
    if (lane == 0) lds[wv] = acc;
    __syncthreads();
    int prefix = lds[0] + lds[1] + lds[2] + lds[3];
    int i = lim + tid;
    int v = (i < N_NODES) ? cnt[i] : 0;
    int inc = v;
#pragma unroll
    for (int off = 1; off < 64; off <<= 1) {
        int t2 = __shfl_up(inc, off, 64);
        if (lane >= off) inc += t2;
    }
    if (lane == 63) lds[4 + wv] = inc;
    __syncthreads();
    int woff = 0;
    for (int j = 0; j < wv; j++) woff += lds[4 + j];
    int rs = prefix + woff + (inc - v);
    if (i < N_NODES) row_start[i] = rs;
    if (i == N_NODES) row_start[N_NODES] = rs;
}

// ---------------------------------------------------------------------------
// permute_k: atomic-free. pos = row_start[dst] + rank[e].
// ---------------------------------------------------------------------------
__global__ __launch_bounds__(256) void permute_k(const int* __restrict__ ei,
                                                 const int* __restrict__ row_start,
                                                 const int* __restrict__ rank,
                                                 int* __restrict__ sorted_src) {
    int e = blockIdx.x * 256 + threadIdx.x;
    if (e >= N_EDGES) return;
    int dst = ei[N_EDGES + e];
    int pos = row_start[dst] + rank[e];
    sorted_src[pos] = ei[e];
}

// ---------------------------------------------------------------------------
// agg_k (R6-proven): one wave per node. lane=(g=lane>>4, sub=lane&15); one
// b128 load covers 4 edges, unroll x2 = 8 edges (2KB) in flight;
// shfl_xor(16,32) folds edge groups; writes bf16 mean to Abf cols 0..127.
// ---------------------------------------------------------------------------
__global__ __launch_bounds__(256) void agg_k(const int* __restrict__ row_start,
                                             const int* __restrict__ sorted_src,
                                             unsigned int* __restrict__ Abf_u) {
    int wid  = (blockIdx.x * 256 + threadIdx.x) >> 6;  // node, < N exactly
    int lane = threadIdx.x & 63;
    int g    = lane >> 4;
    int sub  = lane & 15;
    int beg = row_start[wid];
    int end = row_start[wid + 1];
    const uint4* X = reinterpret_cast<const uint4*>(Abf_u);  // row = 32 uint4

    float s[8];
#pragma unroll
    for (int j = 0; j < 8; j++) s[j] = 0.f;

    for (int i = beg; i < end; i += 8) {
        int e0 = i + g;
        int e1 = i + 4 + g;
        uint4 v0 = make_uint4(0, 0, 0, 0), v1 = make_uint4(0, 0, 0, 0);
        if (e0 < end) v0 = X[(size_t)sorted_src[e0] * 32 + 16 + sub];
        if (e1 < end) v1 = X[(size_t)sorted_src[e1] * 32 + 16 + sub];
        s[0] += bf2f(v0.x & 0xffffu) + bf2f(v1.x & 0xffffu);
        s[1] += bf2f(v0.x >> 16)     + bf2f(v1.x >> 16);
        s[2] += bf2f(v0.y & 0xffffu) + bf2f(v1.y & 0xffffu);
        s[3] += bf2f(v0.y >> 16)     + bf2f(v1.y >> 16);
        s[4] += bf2f(v0.z & 0xffffu) + bf2f(v1.z & 0xffffu);
        s[5] += bf2f(v0.z >> 16)     + bf2f(v1.z >> 16);
        s[6] += bf2f(v0.w & 0xffffu) + bf2f(v1.w & 0xffffu);
        s[7] += bf2f(v0.w >> 16)     + bf2f(v1.w >> 16);
    }

#pragma unroll
    for (int m = 16; m <= 32; m <<= 1)
#pragma unroll
        for (int j = 0; j < 8; j++) s[j] += __shfl_xor(s[j], m, 64);

    if (g == 0) {
        float inv = (end > beg) ? 1.0f / (float)(end - beg) : 0.0f;
        uint4 o;
        o.x = (unsigned int)f2bf(s[0] * inv) | ((unsigned int)f2bf(s[1] * inv) << 16);
        o.y = (unsigned int)f2bf(s[2] * inv) | ((unsigned int)f2bf(s[3] * inv) << 16);
        o.z = (unsigned int)f2bf(s[4] * inv) | ((unsigned int)f2bf(s[5] * inv) << 16);
        o.w = (unsigned int)f2bf(s[6] * inv) | ((unsigned int)f2bf(s[7] * inv) << 16);
        reinterpret_cast<uint4*>(Abf_u)[(size_t)wid * 32 + sub] = o;
    }
}

// ---------------------------------------------------------------------------
// gemm_k (R6): stage full 64x256 A-tile, ONE barrier, barrier-free K-loop,
// B-frags straight from L2-resident Wimg.
// ---------------------------------------------------------------------------
__global__ __launch_bounds__(256) void gemm_k(const unsigned short* __restrict__ Abf,
                                              const unsigned short* __restrict__ Wimg,
                                              const float* __restrict__ bl,
                                              float* __restrict__ out) {
    __shared__ unsigned short As[64 * 264];

    int tid  = threadIdx.x;
    int w    = tid >> 6;
    int lane = tid & 63;
    int m15  = lane & 15;
    int quad = lane >> 4;
    int bm   = blockIdx.x * 64;

#pragma unroll
    for (int s = 0; s < 8; s++) {
        int idx = s * 256 + tid;
        int r = idx >> 5, c = idx & 31;
        int grow = bm + r;
        short8 v = {0, 0, 0, 0, 0, 0, 0, 0};
        if (grow < N_NODES)
            v = *reinterpret_cast<const short8*>(Abf + (size_t)grow * 256 + c * 8);
        *reinterpret_cast<short8*>(As + r * 264 + c * 8) = v;
    }
    __syncthreads();  // the only barrier

    f32x4 zero4 = {0.f, 0.f, 0.f, 0.f};
    f32x4 acc[4][4];
#pragma unroll
    for (int rt = 0; rt < 4; rt++)
#pragma unroll
        for (int ct = 0; ct < 4; ct++) acc[rt][ct] = zero4;

#pragma unroll
    for (int kc = 0; kc < 8; kc++) {
        short8 Af[4], Bf[4];
#pragma unroll
        for (int rt = 0; rt < 4; rt++)
            Af[rt] = *reinterpret_cast<const short8*>(
                         As + (rt * 16 + m15) * 264 + kc * 32 + quad * 8);
#pragma unroll
        for (int ct = 0; ct < 4; ct++)
            Bf[ct] = *reinterpret_cast<const short8*>(
                         Wimg + (size_t)kc * 8192 +
                         (w * 64 + ct * 16 + m15) * 32 + quad * 8);
#pragma unroll
        for (int rt = 0; rt < 4; rt++)
#pragma unroll
            for (int ct = 0; ct < 4; ct++)
                acc[rt][ct] = __builtin_amdgcn_mfma_f32_16x16x32_bf16(
                    Af[rt], Bf[ct], acc[rt][ct], 0, 0, 0);
    }

    float bias[4];
#pragma unroll
    for (int ct = 0; ct < 4; ct++) bias[ct] = bl[w * 64 + ct * 16 + m15];
#pragma unroll
    for (int rt = 0; rt < 4; rt++) {
        int rb = bm + rt * 16 + quad * 4;
#pragma unroll
        for (int r = 0; r < 4; r++) {
            int row = rb + r;
            if (row < N_NODES) {
#pragma unroll
                for (int ct = 0; ct < 4; ct++)
                    out[(size_t)row * 256 + w * 64 + ct * 16 + m15] =
                        acc[rt][ct][r] + bias[ct];
            }
        }
    }
}

extern "C" void kernel_launch(void* const* d_in, const int* in_sizes, int n_in,
                              void* d_out, int out_size, void* d_ws, size_t ws_size,
                              hipStream_t stream) {
    const float* x  = (const float*)d_in[0];
    const int*   ei = (const int*)d_in[1];   // [2, E] int32
    const float* Wl = (const float*)d_in[2];
    const float* bl = (const float*)d_in[3];
    const float* Wr = (const float*)d_in[4];
    float* out = (float*)d_out;

    // ws layout
    unsigned short* Abf  = (unsigned short*)d_ws;              // N*256 bf16
    unsigned short* Wimg = Abf + (size_t)N_NODES * 256;        // 65536 bf16
    int* cnt        = (int*)(Wimg + 65536);                    // N
    int* row_start  = cnt + N_NODES;                           // N+1
    int* rank       = row_start + N_NODES + 1;                 // E
    int* sorted_src = rank + N_EDGES;                          // E

    hipMemsetAsync(cnt, 0, N_NODES * sizeof(int), stream);

    prep_k<<<HIST_BLOCKS + PREPX_BLOCKS + WPREP_BLOCKS, 256, 0, stream>>>(
        x, ei, Wl, Wr, (unsigned int*)Abf, Wimg, cnt, rank);
    scan_full_k<<<SCAN_BLOCKS, 256, 0, stream>>>(cnt, row_start);
    permute_k<<<(N_EDGES + 255) / 256, 256, 0, stream>>>(ei, row_start, rank,
                                                         sorted_src);
    agg_k<<<(N_NODES * 64) / 256, 256, 0, stream>>>(row_start, sorted_src,
                                                    (unsigned int*)Abf);
    gemm_k<<<(N_NODES + 63) / 64, 256, 0, stream>>>(Abf, Wimg, bl, out);
}